// Round 2
// baseline (2177.266 us; speedup 1.0000x reference)
//
#include <hip/hip_runtime.h>
#include <hip/hip_bf16.h>
#include <stdint.h>

// Persistent-RNN, R6: halved all-to-all redundancy via 128-col blocks + hi-only weights.
//  - 64 blocks x 512 threads (8 waves). 8 batch-groups x 8 col-partitions.
//  - Block (g,p): batch rows [16g,16g+16), hidden cols [128p,128p+128).
//  - R5 -> R6:
//      * cols/block 64 -> 128: each chain's state is re-read by 8 blocks instead
//        of 16 -> total poll traffic 8 MB -> 4 MB per sweep; each producer gates
//        8 consumer waves instead of 16. Register cost paid by dropping the
//        W_hh/W_ih lo-fragments (hi-only bf16 weights, FULL hi+lo state kept):
//        products (s_hi + s_lo) * W_hi. Weight-quant error ~2e-4/step, recurrence
//        contraction (||W||~0.58) keeps it bounded; predicted absmax ~3-5e-3.
//      * slice p == producer block p: each consumer wave waits on exactly ONE
//        producer block (was 2).
//      * chain-per-XCD heuristic: g = blockIdx.x & 7 (round-robin dispatch puts
//        a chain's 8 blocks on one XCD; perf-only, correctness-independent).
//      * reduction single-buffered red[8][16][128] (64 KB), 2 barriers/step.
//  - Tag protocol unchanged: u32 = (bf16hi<<16)|(bf16lo&~1|parity); consumer
//    polls its 8 KB slice until all 32 tags match (t>>1)&1; passing sweep IS
//    the load. WAR safety: producer can only write state(t+2) after consuming
//    state(t+1), which requires every block to have passed its step-t barrier,
//    i.e. all step-t reads retired; same-buffer states have opposite tags.

#define TSTEPS 512
#define BATCH  128
#define NI     256
#define NH     1024
#define NO     128
#define NBLK   64
#define NTHR   512
#define NWAVE  8
#define BG     16
#define COLS   128

typedef __attribute__((ext_vector_type(8))) short s16x8;
typedef __attribute__((ext_vector_type(4))) float f32x4;
typedef __attribute__((ext_vector_type(4))) unsigned u32x4;
typedef unsigned long long ull;

__device__ __forceinline__ unsigned short f2bf_rne(float f) {
  unsigned u = __builtin_bit_cast(unsigned, f);
  unsigned r = u + 0x7fffu + ((u >> 16) & 1u);
  return (unsigned short)(r >> 16);
}
__device__ __forceinline__ float bf2f(unsigned short h) {
  unsigned u = ((unsigned)h) << 16;
  return __builtin_bit_cast(float, u);
}
__device__ __forceinline__ void split_bf(float v, short &hi, short &lo) {
  unsigned short h = f2bf_rne(v);
  hi = (short)h;
  lo = (short)f2bf_rne(v - bf2f(h));
}
__device__ __forceinline__ f32x4 mfma16(s16x8 a, s16x8 b, f32x4 c) {
  return __builtin_amdgcn_mfma_f32_16x16x32_bf16(a, b, c, 0, 0, 0);
}
__device__ __forceinline__ float fast_tanh(float a) {
  float cl = fminf(fmaxf(a, -15.f), 15.f);
  float e  = __expf(2.f * cl);
  return (e - 1.f) / (e + 1.f);
}

// state u32 index: [g 0..8)[slice 0..8)[r 0..16)[k_local 0..128)
//   global K / hidden col = slice*128 + k_local ; batch row = g*16 + r
//   slice p is written by producer block (g,p) and polled by wave p of each
//   consumer block in group g.
#define SIDX(g, p, r, k) ((((size_t)(g) * NWAVE + (p)) * BG + (r)) * 128 + (k))

__global__ __launch_bounds__(NTHR, 2)
void rnn_persistent(const float* __restrict__ x,
                    const float* __restrict__ W_ih,
                    const float* __restrict__ W_hh,
                    const float* __restrict__ b_ih,
                    const float* __restrict__ b_hh,
                    unsigned*    __restrict__ SP)    // [2][8][8][16][128] tagged packed state
{
  const int tid  = threadIdx.x;
  const int wave = tid >> 6;
  const int lane = tid & 63;
  const int lr   = lane & 15;
  const int lq   = lane >> 4;
  const int g    = blockIdx.x & 7;     // 8 groups, one chain per XCD (heuristic)
  const int p    = blockIdx.x >> 3;    // 8 col-partitions per group
  const int row0 = g * BG;
  const int h0   = p * COLS;
  const int kq0  = wave * 128;         // this wave's hidden-K slice (== slice 'wave')
  const int iq0  = wave * 32;          // this wave's input-K slice

  __shared__ float red[NWAVE][BG][COLS];   // 64 KB, single-buffered (2 barriers/step)

  // ---- persistent W_hh B-fragments, HI-ONLY: [n-tile 0..7][kb 0..3] ----
  // B[k][n] = W_hh[h0+n][k]; lane holds n = lane&15, k = kq0+kb*32+quad*8+j.
  s16x8 whh[8][4];
  #pragma unroll
  for (int nt = 0; nt < 8; ++nt) {
    const int h = h0 + nt * 16 + lr;
    #pragma unroll
    for (int kb = 0; kb < 4; ++kb) {
      const float* pw = W_hh + (size_t)h * NH + kq0 + kb * 32 + lq * 8;
      s16x8 hi;
      #pragma unroll
      for (int j = 0; j < 8; ++j) hi[j] = (short)f2bf_rne(pw[j]);
      whh[nt][kb] = hi;
    }
  }
  // ---- persistent W_ih B-fragments, HI-ONLY: [n-tile 0..7], 32-wide k ----
  s16x8 wih[8];
  #pragma unroll
  for (int nt = 0; nt < 8; ++nt) {
    const int h = h0 + nt * 16 + lr;
    const float* pw = W_ih + (size_t)h * NI + iq0 + lq * 8;
    s16x8 hi;
    #pragma unroll
    for (int j = 0; j < 8; ++j) hi[j] = (short)f2bf_rne(pw[j]);
    wih[nt] = hi;
  }

  // epilogue ownership: thread -> row tid>>5, cols 4*(tid&31) .. +3
  const int er = tid >> 5;
  const int ec = (tid & 31) * 4;
  float bias[4];
  #pragma unroll
  for (int j = 0; j < 4; ++j) bias[j] = b_ih[h0 + ec + j] + b_hh[h0 + ec + j];

  unsigned* buf0 = SP;
  unsigned* buf1 = SP + (size_t)BATCH * NH;

  // x prefetch registers (step 0)
  float xf[8];
  {
    const float* xp = x + (size_t)(row0 + lr) * NI + iq0 + lq * 8;
    #pragma unroll
    for (int j = 0; j < 8; ++j) xf[j] = xp[j];
  }

  // consumer poll base: wave 'wave' polls slice 'wave' (producer block (g,wave))
  const unsigned* sb0 = buf0 + SIDX(g, wave, lr, lq * 8);
  const unsigned* sb1 = buf1 + SIDX(g, wave, lr, lq * 8);

  for (int t = 0; t < TSTEPS; ++t) {
    // ---------- x projection from prefetched registers (2-product, hi-only W) ----------
    f32x4 acc[8];
    #pragma unroll
    for (int nt = 0; nt < 8; ++nt) acc[nt] = (f32x4){0.f, 0.f, 0.f, 0.f};
    {
      s16x8 xhi, xlo;
      #pragma unroll
      for (int j = 0; j < 8; ++j) { short a, b; split_bf(xf[j], a, b); xhi[j] = a; xlo[j] = b; }
      #pragma unroll
      for (int nt = 0; nt < 8; ++nt) {
        acc[nt] = mfma16(xhi, wih[nt], acc[nt]);
        acc[nt] = mfma16(xlo, wih[nt], acc[nt]);
      }
    }
    // ---------- poll own slice until all 32 tags match; passing sweep IS the load ----------
    const unsigned etag = (unsigned)((t >> 1) & 1);
    const unsigned* sb = (t & 1) ? sb1 : sb0;
    u32x4 sv0, sv1, sv2, sv3, sv4, sv5, sv6, sv7;
    {
      const u32x4 e4 = (u32x4){etag, etag, etag, etag};
      for (;;) {
        asm volatile(
          "global_load_dwordx4 %0, %8, off sc1\n\t"
          "global_load_dwordx4 %1, %8, off offset:16 sc1\n\t"
          "global_load_dwordx4 %2, %8, off offset:128 sc1\n\t"
          "global_load_dwordx4 %3, %8, off offset:144 sc1\n\t"
          "global_load_dwordx4 %4, %8, off offset:256 sc1\n\t"
          "global_load_dwordx4 %5, %8, off offset:272 sc1\n\t"
          "global_load_dwordx4 %6, %8, off offset:384 sc1\n\t"
          "global_load_dwordx4 %7, %8, off offset:400 sc1\n\t"
          "s_waitcnt vmcnt(0)"
          : "=&v"(sv0), "=&v"(sv1), "=&v"(sv2), "=&v"(sv3),
            "=&v"(sv4), "=&v"(sv5), "=&v"(sv6), "=&v"(sv7)
          : "v"(sb) : "memory");
        u32x4 b4 = (sv0 ^ e4) | (sv1 ^ e4) | (sv2 ^ e4) | (sv3 ^ e4)
                 | (sv4 ^ e4) | (sv5 ^ e4) | (sv6 ^ e4) | (sv7 ^ e4);
        unsigned bad = b4[0] | b4[1] | b4[2] | b4[3];
        if ((bad & 1u) == 0) break;
      }
    }
    // ---------- prefetch x[t+1] (hides HBM latency under MFMA + epilogue) ----------
    {
      const int tn = (t + 1 < TSTEPS) ? (t + 1) : t;
      const float* xp = x + (size_t)tn * BATCH * NI + (size_t)(row0 + lr) * NI + iq0 + lq * 8;
      #pragma unroll
      for (int j = 0; j < 8; ++j) xf[j] = xp[j];
    }
    // ---------- recurrent MFMAs: (s_hi + s_lo) x W_hi, per 32-wide kb ----------
    #pragma unroll
    for (int kb = 0; kb < 4; ++kb) {
      const u32x4 va = (kb == 0) ? sv0 : (kb == 1) ? sv2 : (kb == 2) ? sv4 : sv6;
      const u32x4 vb = (kb == 0) ? sv1 : (kb == 1) ? sv3 : (kb == 2) ? sv5 : sv7;
      s16x8 shi, slo;
      #pragma unroll
      for (int i = 0; i < 4; ++i) {
        unsigned wa = va[i], wb = vb[i];
        shi[i]     = (short)(wa >> 16); slo[i]     = (short)(wa & 0xffffu);
        shi[i + 4] = (short)(wb >> 16); slo[i + 4] = (short)(wb & 0xffffu);
      }
      #pragma unroll
      for (int nt = 0; nt < 8; ++nt) {
        acc[nt] = mfma16(shi, whh[nt][kb], acc[nt]);
        acc[nt] = mfma16(slo, whh[nt][kb], acc[nt]);
      }
    }
    // ---------- cross-wave K reduction (single-buffered -> 2 barriers/step) ----------
    // C/D layout: col = lane&15, row = quad*4 + reg (m89/m91 verified)
    __syncthreads();   // B1: previous step's epilogue reads of red are done
    #pragma unroll
    for (int nt = 0; nt < 8; ++nt)
      #pragma unroll
      for (int r = 0; r < 4; ++r)
        red[wave][lq * 4 + r][nt * 16 + lr] = acc[nt][r];
    __syncthreads();   // B2: all partials visible
    // ---------- epilogue: reduce 8 waves, tanh, tagged store (fire, no drain) ----------
    {
      float s[4] = {bias[0], bias[1], bias[2], bias[3]};
      #pragma unroll
      for (int w = 0; w < NWAVE; ++w) {
        const f32x4 v = *(const f32x4*)&red[w][er][ec];
        s[0] += v[0]; s[1] += v[1]; s[2] += v[2]; s[3] += v[3];
      }
      const unsigned otag = (unsigned)(((t + 1) >> 1) & 1);
      unsigned pkw[4];
      #pragma unroll
      for (int j = 0; j < 4; ++j) {
        float tv = fast_tanh(s[j]);
        unsigned short hb = f2bf_rne(tv);
        unsigned       lb = ((f2bf_rne(tv - bf2f(hb)) & 0xfffeu) | otag);
        pkw[j] = (((unsigned)hb) << 16) | lb;
      }
      ull pk01 = ((ull)pkw[1] << 32) | (ull)pkw[0];
      ull pk23 = ((ull)pkw[3] << 32) | (ull)pkw[2];
      ull* op = (ull*)(((t + 1) & 1 ? buf1 : buf0) + SIDX(g, p, er, ec));
      __hip_atomic_store(op,     pk01, __ATOMIC_RELAXED, __HIP_MEMORY_SCOPE_AGENT);
      __hip_atomic_store(op + 1, pk23, __ATOMIC_RELAXED, __HIP_MEMORY_SCOPE_AGENT);
    }
  }
}

__global__ __launch_bounds__(256)
void init_buf1(unsigned* __restrict__ SP) {
  // buffer1 stale-tag init: consumers of s=1 expect tag 0 -> mark stale with LSB=1
  const int i = blockIdx.x * 256 + threadIdx.x;
  SP[BATCH * NH + i] = 1u;
}

__global__ __launch_bounds__(512)
void rnn_readout(const unsigned* __restrict__ SP,      // final state = buf0 (T even)
                 const float* __restrict__ W_ro,       // [128][1024]
                 const float* __restrict__ b_ro,       // [128]
                 float* __restrict__ out)              // [128][128]
{
  __shared__ float srow[4][NH];
  const int b0 = blockIdx.x * 4;
  for (int i = threadIdx.x; i < 4 * NH; i += 512) {
    const int b = b0 + (i >> 10);
    const int h = i & 1023;
    unsigned u = SP[SIDX(b >> 4, h >> 7, b & 15, h & 127)];
    srow[i >> 10][h] = bf2f((unsigned short)(u >> 16)) + bf2f((unsigned short)(u & 0xffffu));
  }
  __syncthreads();
  const int bb = threadIdx.x >> 7;
  const int o  = threadIdx.x & 127;
  const float* wr = W_ro + (size_t)o * NH;
  float s = 0.f;
  #pragma unroll 4
  for (int k = 0; k < NH; ++k) s += srow[bb][k] * wr[k];
  out[(size_t)(b0 + bb) * NO + o] = s + b_ro[o];
}

extern "C" void kernel_launch(void* const* d_in, const int* in_sizes, int n_in,
                              void* d_out, int out_size, void* d_ws, size_t ws_size,
                              hipStream_t stream) {
  (void)in_sizes; (void)n_in; (void)out_size; (void)ws_size;
  const float* x    = (const float*)d_in[0];
  const float* W_ih = (const float*)d_in[1];
  const float* W_hh = (const float*)d_in[2];
  const float* b_ih = (const float*)d_in[3];
  const float* b_hh = (const float*)d_in[4];
  const float* W_ro = (const float*)d_in[5];
  const float* b_ro = (const float*)d_in[6];
  float* out = (float*)d_out;

  unsigned* SP = (unsigned*)d_ws;   // [2][128][1024] u32 = 1 MB

  // buf0 = state s=0: zeros, tag LSB=0 (expected tag for s=0 is 0) -> plain memset
  hipMemsetAsync(SP, 0, (size_t)BATCH * NH * sizeof(unsigned), stream);
  // buf1 = stale marker (tag 1 != expected 0 for s=1)
  init_buf1<<<(BATCH * NH) / 256, 256, 0, stream>>>(SP);

  rnn_persistent<<<NBLK, NTHR, 0, stream>>>(x, W_ih, W_hh, b_ih, b_hh, SP);
  // T=512 even -> final state in buf0
  rnn_readout<<<BATCH / 4, 512, 0, stream>>>(SP, W_ro, b_ro, out);
}

// Round 3
// 2109.406 us; speedup vs baseline: 1.0322x; 1.0322x over previous
//
#include <hip/hip_runtime.h>
#include <hip/hip_bf16.h>
#include <stdint.h>

// Persistent-RNN, R7: R5 geometry + cheap 2-line gate before the full tagged sweep.
//  - 128 blocks x 512 threads (8 waves). 8 batch-groups x 16 col-blocks.
//  - Block (g,m): batch rows [16g,16g+16), hidden cols [64m,64m+64).
//  - R5 -> R7 (R6's 128-col/XCD-concentration experiment reverted: it serialized
//    each chain's polls through one XCD's fabric port and regressed):
//      * GATE: before the 8KB verify sweep, each wave spins on 2 cache lines
//        (one dword/lane from row 0 of each of its two producers' half-slices,
//        tag-checked). 2 line-requests/wave/sweep vs 64 -> ~32x less failing-poll
//        fabric pressure. Gate is a HINT only; the full tagged sweep (unchanged,
//        retry loop) remains the sole correctness mechanism. Gate exit condition
//        is a subset of verify's -> no deadlock. Producer side unchanged.
//  - Tag protocol: u32 = (bf16hi<<16)|(bf16lo&~1|parity); consumer polls its own
//    data words until all 32 tags == (t>>1)&1; the passing sweep IS the state load.
//  - WAR safety: any fresh word of producer B implies B passed its step-(t-1)
//    block barrier implies all B's step-(t-1) state reads retired; same-buffer
//    consecutive states have opposite tags.

#define TSTEPS 512
#define BATCH  128
#define NI     256
#define NH     1024
#define NO     128
#define NBLK   128
#define NTHR   512
#define NWAVE  8
#define BG     16
#define COLS   64

typedef __attribute__((ext_vector_type(8))) short s16x8;
typedef __attribute__((ext_vector_type(4))) float f32x4;
typedef __attribute__((ext_vector_type(4))) unsigned u32x4;
typedef unsigned long long ull;

__device__ __forceinline__ unsigned short f2bf_rne(float f) {
  unsigned u = __builtin_bit_cast(unsigned, f);
  unsigned r = u + 0x7fffu + ((u >> 16) & 1u);
  return (unsigned short)(r >> 16);
}
__device__ __forceinline__ float bf2f(unsigned short h) {
  unsigned u = ((unsigned)h) << 16;
  return __builtin_bit_cast(float, u);
}
__device__ __forceinline__ void split_bf(float v, short &hi, short &lo) {
  unsigned short h = f2bf_rne(v);
  hi = (short)h;
  lo = (short)f2bf_rne(v - bf2f(h));
}
__device__ __forceinline__ f32x4 mfma16(s16x8 a, s16x8 b, f32x4 c) {
  return __builtin_amdgcn_mfma_f32_16x16x32_bf16(a, b, c, 0, 0, 0);
}
__device__ __forceinline__ float fast_tanh(float a) {
  float cl = fminf(fmaxf(a, -15.f), 15.f);
  float e  = __expf(2.f * cl);
  return (e - 1.f) / (e + 1.f);
}

// state u32 index: [g 0..8)[w 0..8)[r 0..16)[k_local 0..128)
//   global K = w*128 + k_local ; batch row = g*16 + r
#define SIDX(g, w, r, k) ((((size_t)(g) * NWAVE + (w)) * BG + (r)) * 128 + (k))

__global__ __launch_bounds__(NTHR, 2)
void rnn_persistent(const float* __restrict__ x,
                    const float* __restrict__ W_ih,
                    const float* __restrict__ W_hh,
                    const float* __restrict__ b_ih,
                    const float* __restrict__ b_hh,
                    unsigned*    __restrict__ SP)    // [2][8][8][16][128] tagged packed state
{
  const int tid  = threadIdx.x;
  const int wave = tid >> 6;
  const int lane = tid & 63;
  const int lr   = lane & 15;
  const int lq   = lane >> 4;
  const int g    = blockIdx.x >> 4;    // 8 groups (natural mapping: group spread over XCDs)
  const int m    = blockIdx.x & 15;    // 16 col-blocks per group
  const int row0 = g * BG;
  const int h0   = m * COLS;
  const int kq0  = wave * 128;         // this wave's hidden-K slice
  const int iq0  = wave * 32;          // this wave's input-K slice

  __shared__ float red[2][NWAVE][1024];

  // ---- persistent W_hh B-fragments: [n-tile 0..3][kb 0..3], hi/lo ----
  // B[k][n] = W_hh[h0+n][k]; lane holds n = lane&15, k = kq0+kb*32+quad*8+j.
  s16x8 whh_hi[4][4], whh_lo[4][4];
  #pragma unroll
  for (int nt = 0; nt < 4; ++nt) {
    const int h = h0 + nt * 16 + lr;
    #pragma unroll
    for (int kb = 0; kb < 4; ++kb) {
      const float* p = W_hh + (size_t)h * NH + kq0 + kb * 32 + lq * 8;
      s16x8 hi, lo;
      #pragma unroll
      for (int j = 0; j < 8; ++j) { short a, b; split_bf(p[j], a, b); hi[j] = a; lo[j] = b; }
      whh_hi[nt][kb] = hi; whh_lo[nt][kb] = lo;
    }
  }
  // ---- persistent W_ih B-fragments: [n-tile 0..3], single 32-wide kb ----
  s16x8 wih_hi[4], wih_lo[4];
  #pragma unroll
  for (int nt = 0; nt < 4; ++nt) {
    const int h = h0 + nt * 16 + lr;
    const float* p = W_ih + (size_t)h * NI + iq0 + lq * 8;
    s16x8 hi, lo;
    #pragma unroll
    for (int j = 0; j < 8; ++j) { short a, b; split_bf(p[j], a, b); hi[j] = a; lo[j] = b; }
    wih_hi[nt] = hi; wih_lo[nt] = lo;
  }

  // epilogue ownership: thread -> row tid>>5, cols 2*(tid&31), +1
  const int er = tid >> 5;
  const int ec = (tid & 31) * 2;
  const float bias0 = b_ih[h0 + ec]     + b_hh[h0 + ec];
  const float bias1 = b_ih[h0 + ec + 1] + b_hh[h0 + ec + 1];
  const int wsl = m >> 1;              // wave-slice this block's cols land in
  const int klo = (m & 1) * 64 + ec;   // k_local of this thread's pair

  unsigned* buf0 = SP;
  unsigned* buf1 = SP + (size_t)BATCH * NH;

  // x prefetch registers (step 0)
  float xf[8];
  {
    const float* xp = x + (size_t)(row0 + lr) * NI + iq0 + lq * 8;
    #pragma unroll
    for (int j = 0; j < 8; ++j) xf[j] = xp[j];
  }

  // consumer poll base: this wave's contiguous slice, per-lane fragment offset
  const unsigned* sb0 = buf0 + SIDX(g, wave, lr, lq * 8);
  const unsigned* sb1 = buf1 + SIDX(g, wave, lr, lq * 8);
  // gate base: row 0 of this wave's slice; lane polls dword (lane&31) of each
  // producer half (k_local [0,32) from producer 2*wave, [64,96) from 2*wave+1)
  const unsigned* gb0 = buf0 + SIDX(g, wave, 0, 0) + (lane & 31);
  const unsigned* gb1 = buf1 + SIDX(g, wave, 0, 0) + (lane & 31);

  for (int t = 0; t < TSTEPS; ++t) {
    // ---------- x projection from prefetched registers ----------
    f32x4 acc[4];
    #pragma unroll
    for (int nt = 0; nt < 4; ++nt) acc[nt] = (f32x4){0.f, 0.f, 0.f, 0.f};
    {
      s16x8 xhi, xlo;
      #pragma unroll
      for (int j = 0; j < 8; ++j) { short a, b; split_bf(xf[j], a, b); xhi[j] = a; xlo[j] = b; }
      #pragma unroll
      for (int nt = 0; nt < 4; ++nt) {
        acc[nt] = mfma16(xhi, wih_hi[nt], acc[nt]);
        acc[nt] = mfma16(xhi, wih_lo[nt], acc[nt]);
        acc[nt] = mfma16(xlo, wih_hi[nt], acc[nt]);
      }
    }
    const unsigned etag = (unsigned)((t >> 1) & 1);
    // ---------- GATE: spin on 2 cache lines until their tags flip (hint only) ----------
    {
      const unsigned* gp = (t & 1) ? gb1 : gb0;
      for (;;) {
        unsigned f0 = __hip_atomic_load(gp,      __ATOMIC_RELAXED, __HIP_MEMORY_SCOPE_AGENT);
        unsigned f1 = __hip_atomic_load(gp + 64, __ATOMIC_RELAXED, __HIP_MEMORY_SCOPE_AGENT);
        unsigned bad = ((f0 ^ etag) | (f1 ^ etag)) & 1u;
        if (__ballot(bad != 0) == 0ull) break;
      }
    }
    // ---------- verify sweep: all 32 tags must match; passing sweep IS the load ----------
    const unsigned* sb = (t & 1) ? sb1 : sb0;
    u32x4 sv0, sv1, sv2, sv3, sv4, sv5, sv6, sv7;
    {
      const u32x4 e4 = (u32x4){etag, etag, etag, etag};
      for (;;) {
        asm volatile(
          "global_load_dwordx4 %0, %8, off sc1\n\t"
          "global_load_dwordx4 %1, %8, off offset:16 sc1\n\t"
          "global_load_dwordx4 %2, %8, off offset:128 sc1\n\t"
          "global_load_dwordx4 %3, %8, off offset:144 sc1\n\t"
          "global_load_dwordx4 %4, %8, off offset:256 sc1\n\t"
          "global_load_dwordx4 %5, %8, off offset:272 sc1\n\t"
          "global_load_dwordx4 %6, %8, off offset:384 sc1\n\t"
          "global_load_dwordx4 %7, %8, off offset:400 sc1\n\t"
          "s_waitcnt vmcnt(0)"
          : "=&v"(sv0), "=&v"(sv1), "=&v"(sv2), "=&v"(sv3),
            "=&v"(sv4), "=&v"(sv5), "=&v"(sv6), "=&v"(sv7)
          : "v"(sb) : "memory");
        u32x4 b4 = (sv0 ^ e4) | (sv1 ^ e4) | (sv2 ^ e4) | (sv3 ^ e4)
                 | (sv4 ^ e4) | (sv5 ^ e4) | (sv6 ^ e4) | (sv7 ^ e4);
        unsigned bad = b4[0] | b4[1] | b4[2] | b4[3];
        if ((bad & 1u) == 0) break;
      }
    }
    // ---------- prefetch x[t+1] (hides HBM latency under MFMA + epilogue) ----------
    {
      const int tn = (t + 1 < TSTEPS) ? (t + 1) : t;
      const float* xp = x + (size_t)tn * BATCH * NI + (size_t)(row0 + lr) * NI + iq0 + lq * 8;
      #pragma unroll
      for (int j = 0; j < 8; ++j) xf[j] = xp[j];
    }
    // ---------- recurrent MFMAs (unpack + 3-product bf16x2) ----------
    {
      unsigned sw[32];
      #pragma unroll
      for (int e = 0; e < 4; ++e) {
        sw[0  + e] = sv0[e]; sw[4  + e] = sv1[e];
        sw[8  + e] = sv2[e]; sw[12 + e] = sv3[e];
        sw[16 + e] = sv4[e]; sw[20 + e] = sv5[e];
        sw[24 + e] = sv6[e]; sw[28 + e] = sv7[e];
      }
      #pragma unroll
      for (int kb = 0; kb < 4; ++kb) {
        s16x8 shi, slo;
        #pragma unroll
        for (int j = 0; j < 8; ++j) {
          unsigned w = sw[kb * 8 + j];
          shi[j] = (short)(w >> 16);
          slo[j] = (short)(w & 0xffffu);
        }
        #pragma unroll
        for (int nt = 0; nt < 4; ++nt) {
          acc[nt] = mfma16(shi, whh_hi[nt][kb], acc[nt]);
          acc[nt] = mfma16(shi, whh_lo[nt][kb], acc[nt]);
          acc[nt] = mfma16(slo, whh_hi[nt][kb], acc[nt]);
        }
      }
    }
    // ---------- cross-wave K reduction (double-buffered -> ONE barrier/step) ----------
    // C/D layout: col = lane&15, row = quad*4 + reg (m89/m91 verified)
    const int rbi = t & 1;
    #pragma unroll
    for (int nt = 0; nt < 4; ++nt)
      #pragma unroll
      for (int r = 0; r < 4; ++r)
        red[rbi][wave][(lq * 4 + r) * 64 + nt * 16 + lr] = acc[nt][r];
    __syncthreads();
    // ---------- epilogue: reduce 8 waves, tanh, tagged store (fire, no drain) ----------
    {
      float s0 = bias0, s1 = bias1;
      #pragma unroll
      for (int w = 0; w < NWAVE; ++w) {
        float2 v = *(const float2*)&red[rbi][w][er * 64 + ec];
        s0 += v.x; s1 += v.y;
      }
      float t0 = fast_tanh(s0), t1 = fast_tanh(s1);
      const unsigned otag = (unsigned)(((t + 1) >> 1) & 1);
      unsigned short h0b = f2bf_rne(t0);
      unsigned       l0b = ((f2bf_rne(t0 - bf2f(h0b)) & 0xfffeu) | otag);
      unsigned short h1b = f2bf_rne(t1);
      unsigned       l1b = ((f2bf_rne(t1 - bf2f(h1b)) & 0xfffeu) | otag);
      ull pk = ((ull)(((unsigned)h1b << 16) | l1b) << 32)
             |  (ull)(((unsigned)h0b << 16) | l0b);
      ull* op = (ull*)(((t + 1) & 1 ? buf1 : buf0) + SIDX(g, wsl, er, klo));
      __hip_atomic_store(op, pk, __ATOMIC_RELAXED, __HIP_MEMORY_SCOPE_AGENT);
    }
  }
}

__global__ __launch_bounds__(256)
void init_buf1(unsigned* __restrict__ SP) {
  // buffer1 stale-tag init: consumers of s=1 expect tag 0 -> mark stale with LSB=1
  const int i = blockIdx.x * 256 + threadIdx.x;
  SP[BATCH * NH + i] = 1u;
}

__global__ __launch_bounds__(512)
void rnn_readout(const unsigned* __restrict__ SP,      // final state = buf0 (T even)
                 const float* __restrict__ W_ro,       // [128][1024]
                 const float* __restrict__ b_ro,       // [128]
                 float* __restrict__ out)              // [128][128]
{
  __shared__ float srow[4][NH];
  const int b0 = blockIdx.x * 4;
  for (int i = threadIdx.x; i < 4 * NH; i += 512) {
    const int b = b0 + (i >> 10);
    const int h = i & 1023;
    unsigned u = SP[SIDX(b >> 4, h >> 7, b & 15, h & 127)];
    srow[i >> 10][h] = bf2f((unsigned short)(u >> 16)) + bf2f((unsigned short)(u & 0xffffu));
  }
  __syncthreads();
  const int bb = threadIdx.x >> 7;
  const int o  = threadIdx.x & 127;
  const float* wr = W_ro + (size_t)o * NH;
  float s = 0.f;
  #pragma unroll 4
  for (int k = 0; k < NH; ++k) s += srow[bb][k] * wr[k];
  out[(size_t)(b0 + bb) * NO + o] = s + b_ro[o];
}

extern "C" void kernel_launch(void* const* d_in, const int* in_sizes, int n_in,
                              void* d_out, int out_size, void* d_ws, size_t ws_size,
                              hipStream_t stream) {
  (void)in_sizes; (void)n_in; (void)out_size; (void)ws_size;
  const float* x    = (const float*)d_in[0];
  const float* W_ih = (const float*)d_in[1];
  const float* W_hh = (const float*)d_in[2];
  const float* b_ih = (const float*)d_in[3];
  const float* b_hh = (const float*)d_in[4];
  const float* W_ro = (const float*)d_in[5];
  const float* b_ro = (const float*)d_in[6];
  float* out = (float*)d_out;

  unsigned* SP = (unsigned*)d_ws;   // [2][128][1024] u32 = 1 MB

  // buf0 = state s=0: zeros, tag LSB=0 (expected tag for s=0 is 0) -> plain memset
  hipMemsetAsync(SP, 0, (size_t)BATCH * NH * sizeof(unsigned), stream);
  // buf1 = stale marker (tag 1 != expected 0 for s=1)
  init_buf1<<<(BATCH * NH) / 256, 256, 0, stream>>>(SP);

  rnn_persistent<<<NBLK, NTHR, 0, stream>>>(x, W_ih, W_hh, b_ih, b_hh, SP);
  // T=512 even -> final state in buf0
  rnn_readout<<<BATCH / 4, 512, 0, stream>>>(SP, W_ro, b_ro, out);
}

// Round 4
// 1836.978 us; speedup vs baseline: 1.1852x; 1.1483x over previous
//
#include <hip/hip_runtime.h>
#include <hip/hip_bf16.h>
#include <stdint.h>

// Persistent-RNN, R8: L2-scope exchange via XCD-concentrated groups + dual-scope poll.
//  - 128 blocks x 512 threads (8 waves). 8 batch-groups x 16 col-blocks.
//  - Block (g,m): g = blockIdx&7 (one group per XCD under round-robin dispatch),
//    m = blockIdx>>3. Batch rows [16g,16g+16), hidden cols [64m,64m+64).
//  - R5 -> R8 (R7's gate removed: it added a serialized RT and regressed,
//    falsifying the congestion theory -> the chain is IC-ROUND-TRIP latency):
//      * Group concentrated on ONE XCD: producer sc1 stores update the local L2
//        on their way to the coherence point, so co-resident consumers can
//        detect+load at L2 latency (~200cy) instead of IC latency (~900cy).
//      * Dual-scope poll: alternate sc0 sweeps (bypass L1, hit L2 - fast path)
//        with sc1 sweeps (IC truth - liveness). Whichever passes IS the state
//        load. Correctness never depends on placement or sc0 semantics:
//        same-buffer consecutive states carry opposite per-dword parity tags,
//        so stale L2 lines cannot false-pass; the sc1 sweep (exactly R5's
//        proven mechanism) guarantees progress if blocks land cross-XCD.
//  - Tag protocol: u32 = (bf16hi<<16)|(bf16lo&~1|parity); consumer polls its own
//    data words until all 32 tags == (t>>1)&1.
//  - WAR safety: any fresh word of producer B implies B passed its step-(t-1)
//    block barrier implies all B's step-(t-1) state reads retired.

#define TSTEPS 512
#define BATCH  128
#define NI     256
#define NH     1024
#define NO     128
#define NBLK   128
#define NTHR   512
#define NWAVE  8
#define BG     16
#define COLS   64

typedef __attribute__((ext_vector_type(8))) short s16x8;
typedef __attribute__((ext_vector_type(4))) float f32x4;
typedef __attribute__((ext_vector_type(4))) unsigned u32x4;
typedef unsigned long long ull;

__device__ __forceinline__ unsigned short f2bf_rne(float f) {
  unsigned u = __builtin_bit_cast(unsigned, f);
  unsigned r = u + 0x7fffu + ((u >> 16) & 1u);
  return (unsigned short)(r >> 16);
}
__device__ __forceinline__ float bf2f(unsigned short h) {
  unsigned u = ((unsigned)h) << 16;
  return __builtin_bit_cast(float, u);
}
__device__ __forceinline__ void split_bf(float v, short &hi, short &lo) {
  unsigned short h = f2bf_rne(v);
  hi = (short)h;
  lo = (short)f2bf_rne(v - bf2f(h));
}
__device__ __forceinline__ f32x4 mfma16(s16x8 a, s16x8 b, f32x4 c) {
  return __builtin_amdgcn_mfma_f32_16x16x32_bf16(a, b, c, 0, 0, 0);
}
__device__ __forceinline__ float fast_tanh(float a) {
  float cl = fminf(fmaxf(a, -15.f), 15.f);
  float e  = __expf(2.f * cl);
  return (e - 1.f) / (e + 1.f);
}

// state u32 index: [g 0..8)[w 0..8)[r 0..16)[k_local 0..128)
//   global K = w*128 + k_local ; batch row = g*16 + r
#define SIDX(g, w, r, k) ((((size_t)(g) * NWAVE + (w)) * BG + (r)) * 128 + (k))

__global__ __launch_bounds__(NTHR, 2)
void rnn_persistent(const float* __restrict__ x,
                    const float* __restrict__ W_ih,
                    const float* __restrict__ W_hh,
                    const float* __restrict__ b_ih,
                    const float* __restrict__ b_hh,
                    unsigned*    __restrict__ SP)    // [2][8][8][16][128] tagged packed state
{
  const int tid  = threadIdx.x;
  const int wave = tid >> 6;
  const int lane = tid & 63;
  const int lr   = lane & 15;
  const int lq   = lane >> 4;
  const int g    = blockIdx.x & 7;     // group == chain == XCD (round-robin heuristic)
  const int m    = blockIdx.x >> 3;    // 16 col-blocks per group
  const int row0 = g * BG;
  const int h0   = m * COLS;
  const int kq0  = wave * 128;         // this wave's hidden-K slice
  const int iq0  = wave * 32;          // this wave's input-K slice

  __shared__ float red[2][NWAVE][1024];

  // ---- persistent W_hh B-fragments: [n-tile 0..3][kb 0..3], hi/lo ----
  // B[k][n] = W_hh[h0+n][k]; lane holds n = lane&15, k = kq0+kb*32+quad*8+j.
  s16x8 whh_hi[4][4], whh_lo[4][4];
  #pragma unroll
  for (int nt = 0; nt < 4; ++nt) {
    const int h = h0 + nt * 16 + lr;
    #pragma unroll
    for (int kb = 0; kb < 4; ++kb) {
      const float* p = W_hh + (size_t)h * NH + kq0 + kb * 32 + lq * 8;
      s16x8 hi, lo;
      #pragma unroll
      for (int j = 0; j < 8; ++j) { short a, b; split_bf(p[j], a, b); hi[j] = a; lo[j] = b; }
      whh_hi[nt][kb] = hi; whh_lo[nt][kb] = lo;
    }
  }
  // ---- persistent W_ih B-fragments: [n-tile 0..3], single 32-wide kb ----
  s16x8 wih_hi[4], wih_lo[4];
  #pragma unroll
  for (int nt = 0; nt < 4; ++nt) {
    const int h = h0 + nt * 16 + lr;
    const float* p = W_ih + (size_t)h * NI + iq0 + lq * 8;
    s16x8 hi, lo;
    #pragma unroll
    for (int j = 0; j < 8; ++j) { short a, b; split_bf(p[j], a, b); hi[j] = a; lo[j] = b; }
    wih_hi[nt] = hi; wih_lo[nt] = lo;
  }

  // epilogue ownership: thread -> row tid>>5, cols 2*(tid&31), +1
  const int er = tid >> 5;
  const int ec = (tid & 31) * 2;
  const float bias0 = b_ih[h0 + ec]     + b_hh[h0 + ec];
  const float bias1 = b_ih[h0 + ec + 1] + b_hh[h0 + ec + 1];
  const int wsl = m >> 1;              // wave-slice this block's cols land in
  const int klo = (m & 1) * 64 + ec;   // k_local of this thread's pair

  unsigned* buf0 = SP;
  unsigned* buf1 = SP + (size_t)BATCH * NH;

  // x prefetch registers (step 0)
  float xf[8];
  {
    const float* xp = x + (size_t)(row0 + lr) * NI + iq0 + lq * 8;
    #pragma unroll
    for (int j = 0; j < 8; ++j) xf[j] = xp[j];
  }

  // consumer poll base: this wave's contiguous slice, per-lane fragment offset
  const unsigned* sb0 = buf0 + SIDX(g, wave, lr, lq * 8);
  const unsigned* sb1 = buf1 + SIDX(g, wave, lr, lq * 8);

  for (int t = 0; t < TSTEPS; ++t) {
    // ---------- x projection from prefetched registers ----------
    f32x4 acc[4];
    #pragma unroll
    for (int nt = 0; nt < 4; ++nt) acc[nt] = (f32x4){0.f, 0.f, 0.f, 0.f};
    {
      s16x8 xhi, xlo;
      #pragma unroll
      for (int j = 0; j < 8; ++j) { short a, b; split_bf(xf[j], a, b); xhi[j] = a; xlo[j] = b; }
      #pragma unroll
      for (int nt = 0; nt < 4; ++nt) {
        acc[nt] = mfma16(xhi, wih_hi[nt], acc[nt]);
        acc[nt] = mfma16(xhi, wih_lo[nt], acc[nt]);
        acc[nt] = mfma16(xlo, wih_hi[nt], acc[nt]);
      }
    }
    // ---------- dual-scope poll: sc0 (L2 fast path) alternating sc1 (IC truth) ----------
    const unsigned etag = (unsigned)((t >> 1) & 1);
    const unsigned* sb = (t & 1) ? sb1 : sb0;
    u32x4 sv0, sv1, sv2, sv3, sv4, sv5, sv6, sv7;
    {
      const u32x4 e4 = (u32x4){etag, etag, etag, etag};
      bool use_ic = false;
      for (;;) {
        if (use_ic) {
          asm volatile(
            "global_load_dwordx4 %0, %8, off sc1\n\t"
            "global_load_dwordx4 %1, %8, off offset:16 sc1\n\t"
            "global_load_dwordx4 %2, %8, off offset:128 sc1\n\t"
            "global_load_dwordx4 %3, %8, off offset:144 sc1\n\t"
            "global_load_dwordx4 %4, %8, off offset:256 sc1\n\t"
            "global_load_dwordx4 %5, %8, off offset:272 sc1\n\t"
            "global_load_dwordx4 %6, %8, off offset:384 sc1\n\t"
            "global_load_dwordx4 %7, %8, off offset:400 sc1\n\t"
            "s_waitcnt vmcnt(0)"
            : "=&v"(sv0), "=&v"(sv1), "=&v"(sv2), "=&v"(sv3),
              "=&v"(sv4), "=&v"(sv5), "=&v"(sv6), "=&v"(sv7)
            : "v"(sb) : "memory");
        } else {
          asm volatile(
            "global_load_dwordx4 %0, %8, off sc0\n\t"
            "global_load_dwordx4 %1, %8, off offset:16 sc0\n\t"
            "global_load_dwordx4 %2, %8, off offset:128 sc0\n\t"
            "global_load_dwordx4 %3, %8, off offset:144 sc0\n\t"
            "global_load_dwordx4 %4, %8, off offset:256 sc0\n\t"
            "global_load_dwordx4 %5, %8, off offset:272 sc0\n\t"
            "global_load_dwordx4 %6, %8, off offset:384 sc0\n\t"
            "global_load_dwordx4 %7, %8, off offset:400 sc0\n\t"
            "s_waitcnt vmcnt(0)"
            : "=&v"(sv0), "=&v"(sv1), "=&v"(sv2), "=&v"(sv3),
              "=&v"(sv4), "=&v"(sv5), "=&v"(sv6), "=&v"(sv7)
            : "v"(sb) : "memory");
        }
        u32x4 b4 = (sv0 ^ e4) | (sv1 ^ e4) | (sv2 ^ e4) | (sv3 ^ e4)
                 | (sv4 ^ e4) | (sv5 ^ e4) | (sv6 ^ e4) | (sv7 ^ e4);
        unsigned bad = b4[0] | b4[1] | b4[2] | b4[3];
        if ((bad & 1u) == 0) break;
        use_ic = !use_ic;
      }
    }
    // ---------- prefetch x[t+1] (hides HBM latency under MFMA + epilogue) ----------
    {
      const int tn = (t + 1 < TSTEPS) ? (t + 1) : t;
      const float* xp = x + (size_t)tn * BATCH * NI + (size_t)(row0 + lr) * NI + iq0 + lq * 8;
      #pragma unroll
      for (int j = 0; j < 8; ++j) xf[j] = xp[j];
    }
    // ---------- recurrent MFMAs (unpack + 3-product bf16x2) ----------
    {
      unsigned sw[32];
      #pragma unroll
      for (int e = 0; e < 4; ++e) {
        sw[0  + e] = sv0[e]; sw[4  + e] = sv1[e];
        sw[8  + e] = sv2[e]; sw[12 + e] = sv3[e];
        sw[16 + e] = sv4[e]; sw[20 + e] = sv5[e];
        sw[24 + e] = sv6[e]; sw[28 + e] = sv7[e];
      }
      #pragma unroll
      for (int kb = 0; kb < 4; ++kb) {
        s16x8 shi, slo;
        #pragma unroll
        for (int j = 0; j < 8; ++j) {
          unsigned w = sw[kb * 8 + j];
          shi[j] = (short)(w >> 16);
          slo[j] = (short)(w & 0xffffu);
        }
        #pragma unroll
        for (int nt = 0; nt < 4; ++nt) {
          acc[nt] = mfma16(shi, whh_hi[nt][kb], acc[nt]);
          acc[nt] = mfma16(shi, whh_lo[nt][kb], acc[nt]);
          acc[nt] = mfma16(slo, whh_hi[nt][kb], acc[nt]);
        }
      }
    }
    // ---------- cross-wave K reduction (double-buffered -> ONE barrier/step) ----------
    // C/D layout: col = lane&15, row = quad*4 + reg (m89/m91 verified)
    const int rbi = t & 1;
    #pragma unroll
    for (int nt = 0; nt < 4; ++nt)
      #pragma unroll
      for (int r = 0; r < 4; ++r)
        red[rbi][wave][(lq * 4 + r) * 64 + nt * 16 + lr] = acc[nt][r];
    __syncthreads();
    // ---------- epilogue: reduce 8 waves, tanh, tagged store (fire, no drain) ----------
    {
      float s0 = bias0, s1 = bias1;
      #pragma unroll
      for (int w = 0; w < NWAVE; ++w) {
        float2 v = *(const float2*)&red[rbi][w][er * 64 + ec];
        s0 += v.x; s1 += v.y;
      }
      float t0 = fast_tanh(s0), t1 = fast_tanh(s1);
      const unsigned otag = (unsigned)(((t + 1) >> 1) & 1);
      unsigned short h0b = f2bf_rne(t0);
      unsigned       l0b = ((f2bf_rne(t0 - bf2f(h0b)) & 0xfffeu) | otag);
      unsigned short h1b = f2bf_rne(t1);
      unsigned       l1b = ((f2bf_rne(t1 - bf2f(h1b)) & 0xfffeu) | otag);
      ull pk = ((ull)(((unsigned)h1b << 16) | l1b) << 32)
             |  (ull)(((unsigned)h0b << 16) | l0b);
      ull* op = (ull*)(((t + 1) & 1 ? buf1 : buf0) + SIDX(g, wsl, er, klo));
      __hip_atomic_store(op, pk, __ATOMIC_RELAXED, __HIP_MEMORY_SCOPE_AGENT);
    }
  }
}

__global__ __launch_bounds__(256)
void init_buf1(unsigned* __restrict__ SP) {
  // buffer1 stale-tag init: consumers of s=1 expect tag 0 -> mark stale with LSB=1
  const int i = blockIdx.x * 256 + threadIdx.x;
  SP[BATCH * NH + i] = 1u;
}

__global__ __launch_bounds__(512)
void rnn_readout(const unsigned* __restrict__ SP,      // final state = buf0 (T even)
                 const float* __restrict__ W_ro,       // [128][1024]
                 const float* __restrict__ b_ro,       // [128]
                 float* __restrict__ out)              // [128][128]
{
  __shared__ float srow[4][NH];
  const int b0 = blockIdx.x * 4;
  for (int i = threadIdx.x; i < 4 * NH; i += 512) {
    const int b = b0 + (i >> 10);
    const int h = i & 1023;
    unsigned u = SP[SIDX(b >> 4, h >> 7, b & 15, h & 127)];
    srow[i >> 10][h] = bf2f((unsigned short)(u >> 16)) + bf2f((unsigned short)(u & 0xffffu));
  }
  __syncthreads();
  const int bb = threadIdx.x >> 7;
  const int o  = threadIdx.x & 127;
  const float* wr = W_ro + (size_t)o * NH;
  float s = 0.f;
  #pragma unroll 4
  for (int k = 0; k < NH; ++k) s += srow[bb][k] * wr[k];
  out[(size_t)(b0 + bb) * NO + o] = s + b_ro[o];
}

extern "C" void kernel_launch(void* const* d_in, const int* in_sizes, int n_in,
                              void* d_out, int out_size, void* d_ws, size_t ws_size,
                              hipStream_t stream) {
  (void)in_sizes; (void)n_in; (void)out_size; (void)ws_size;
  const float* x    = (const float*)d_in[0];
  const float* W_ih = (const float*)d_in[1];
  const float* W_hh = (const float*)d_in[2];
  const float* b_ih = (const float*)d_in[3];
  const float* b_hh = (const float*)d_in[4];
  const float* W_ro = (const float*)d_in[5];
  const float* b_ro = (const float*)d_in[6];
  float* out = (float*)d_out;

  unsigned* SP = (unsigned*)d_ws;   // [2][128][1024] u32 = 1 MB

  // buf0 = state s=0: zeros, tag LSB=0 (expected tag for s=0 is 0) -> plain memset
  hipMemsetAsync(SP, 0, (size_t)BATCH * NH * sizeof(unsigned), stream);
  // buf1 = stale marker (tag 1 != expected 0 for s=1)
  init_buf1<<<(BATCH * NH) / 256, 256, 0, stream>>>(SP);

  rnn_persistent<<<NBLK, NTHR, 0, stream>>>(x, W_ih, W_hh, b_ih, b_hh, SP);
  // T=512 even -> final state in buf0
  rnn_readout<<<BATCH / 4, 512, 0, stream>>>(SP, W_ro, b_ro, out);
}